// Round 11
// baseline (165.216 us; speedup 1.0000x reference)
//
#include <hip/hip_runtime.h>
#include <hip/hip_bf16.h>

// n=2,t=16 -> 32 frames; C=64; HW=4096; M=512; 32 groups (2 ch/group).
#define NFRAME 32
#define CCH 64
#define HW 4096
#define MSLOT 512

typedef __attribute__((ext_vector_type(8))) short s16x8;    // 8 bf16 MFMA A/B frag
typedef __attribute__((ext_vector_type(16))) float f32x16;  // 32x32 MFMA C/D frag
typedef __attribute__((ext_vector_type(4))) unsigned int u32x4;
typedef __attribute__((ext_vector_type(2))) unsigned int u32x2;
typedef unsigned short u16;
typedef unsigned int u32;

// f32 workspace offsets
#define WS_STATS 0          // 1024*2 f32
#define WS_OFF   2048       // 32*64 f32
#define WS_BF16  4096       // u16 region starts here (float offset)
// u16 offsets inside bf16 region (fragment-ordered for 32x32x16 MFMA)
#define BW_KF    0                         // [16 q][4 ks][64 l][8]   QK^T A-frags (K rows m)
#define BW_VF    32768                     // [16 q][4 (mh*2+ct)][64 l][8] PV A-frags (V^T rows c)
#define BW_WZF   65536                     // [2 ot][4 ks][64 l][8]   wz A-frags
#define BW_WFF   69632                     // [32 b][2 ot][4 ks][64 l][8] phi A-frags

// exp2-domain scale: 1/sqrt(64) * log2(e)
#define QSCALE 0.18033688011112042f

static __device__ __forceinline__ u16 f2b(float f) {
  __hip_bfloat16 h = __float2bfloat16(f);
  return *reinterpret_cast<u16*>(&h);
}
// bf16 pair pack via v_cvt_pk_bf16_f32 (lane-local pure VALU op; RNE; safe as
// non-volatile asm — r5's miscompile was CROSS-LANE asm, this is arithmetic).
static __device__ __forceinline__ u32 pack2(float a, float b) {
  u32 r;
  asm("v_cvt_pk_bf16_f32 %0, %1, %2" : "=v"(r) : "v"(a), "v"(b));
  return r;
}
static __device__ __forceinline__ f32x16 zero16() {
  f32x16 z;
#pragma unroll
  for (int r = 0; r < 16; ++r) z[r] = 0.f;
  return z;
}
// D-layout -> B-frag transpose (verified r6): input 16 f32 regs e[] holding
// D[row rmap(r,hi)][col l5]; output B-frags f0 (k=0..15), f1 (k=16..31),
// lane row = l5. cvt_pk packs + convergent permlane32_swap builtin.
static __device__ __forceinline__ void d2b(const float* e, s16x8& f0, s16x8& f1) {
#pragma unroll
  for (int mh = 0; mh < 2; ++mh) {
    const u32 P0 = pack2(e[mh * 8 + 0], e[mh * 8 + 1]);
    const u32 P1 = pack2(e[mh * 8 + 2], e[mh * 8 + 3]);
    const u32 Q0 = pack2(e[mh * 8 + 4], e[mh * 8 + 5]);
    const u32 Q1 = pack2(e[mh * 8 + 6], e[mh * 8 + 7]);
    const u32x2 s0 = __builtin_amdgcn_permlane32_swap(P0, Q0, false, false);
    const u32x2 s1 = __builtin_amdgcn_permlane32_swap(P1, Q1, false, false);
    u32x4 bw = {s0[0], s1[0], s0[1], s1[1]};
    if (mh == 0) f0 = __builtin_bit_cast(s16x8, bw);
    else         f1 = __builtin_bit_cast(s16x8, bw);
  }
}

// ---------------- kernel 1: GroupNorm stats (blocks 0..1023) + mb/wz frag tables (1024..1295) ----------------
__global__ __launch_bounds__(256) void k_pre(const float* __restrict__ x,
                                             const float* __restrict__ mb,
                                             const float* __restrict__ wz_w,
                                             float* __restrict__ ws) {
  if (blockIdx.x < 1024) {
    const int bg = blockIdx.x;
    const float4* xp = (const float4*)(x + (size_t)bg * 8192);
    const int t = threadIdx.x;
    float s = 0.f, s2 = 0.f;
#pragma unroll
    for (int i = 0; i < 8; ++i) {
      float4 v = xp[t + i * 256];
      s  += v.x + v.y + v.z + v.w;
      s2 += v.x * v.x + v.y * v.y + v.z * v.z + v.w * v.w;
    }
    for (int off = 32; off; off >>= 1) {
      s  += __shfl_down(s,  off, 64);
      s2 += __shfl_down(s2, off, 64);
    }
    __shared__ float ls[8];
    const int wid = t >> 6;
    if ((t & 63) == 0) { ls[wid * 2] = s; ls[wid * 2 + 1] = s2; }
    __syncthreads();
    if (t == 0) {
      float S = 0.f, S2 = 0.f;
#pragma unroll
      for (int w = 0; w < 4; ++w) { S += ls[w * 2]; S2 += ls[w * 2 + 1]; }
      float mean = S * (1.f / 8192.f);
      float var  = S2 * (1.f / 8192.f) - mean * mean;
      float rstd = rsqrtf(var + 1e-6f);
      ws[WS_STATS + bg * 2]     = mean;
      ws[WS_STATS + bg * 2 + 1] = rstd;
    }
    return;
  }
  // fragment tables
  u16* wbw = (u16*)(ws + WS_BF16);
  const int i = (blockIdx.x - 1024) * 256 + threadIdx.x;
  if (i < 32768) {                           // KF[q][ks][l][j]: m=q*32+(l&31), c=ks*16+(l>>5)*8+j
    const int j = i & 7, l = (i >> 3) & 63, ks = (i >> 9) & 3, q = i >> 11;
    const int c = ks * 16 + ((l >> 5) << 3) + j;
    const int m = q * 32 + (l & 31);
    wbw[BW_KF + i] = f2b(mb[c * MSLOT + m]);
  } else if (i < 65536) {                    // VF[q][mh][ct][l][j]: c=ct*32+(l&31), m=q*32+mh*16+(l>>5)*8+j
    const int i2 = i - 32768;
    const int j = i2 & 7, l = (i2 >> 3) & 63, ct = (i2 >> 9) & 1, mh = (i2 >> 10) & 1, q = i2 >> 11;
    const int c = ct * 32 + (l & 31);
    const int m = q * 32 + mh * 16 + ((l >> 5) << 3) + j;
    wbw[BW_VF + i2] = f2b(mb[c * MSLOT + m]);
  } else {                                   // WZF[ot][ks][l][j]: o=ot*32+(l&31), c=ks*16+(l>>5)*8+j
    const int i3 = i - 65536;
    const int j = i3 & 7, l = (i3 >> 3) & 63, ks = (i3 >> 9) & 3, ot = i3 >> 11;
    const int o = ot * 32 + (l & 31);
    const int c = ks * 16 + ((l >> 5) << 3) + j;
    wbw[BW_WZF + i3] = f2b(wz_w[o * 64 + c]);
  }
}

// ---------------- kernel 2: fold GN + scale into bf16 phi weights, emit frag-ordered WFF ----------------
__global__ __launch_bounds__(256) void k_prep(const float* __restrict__ phi_w,
                                              const float* __restrict__ phi_b,
                                              const float* __restrict__ gamma,
                                              const float* __restrict__ beta,
                                              float* __restrict__ ws) {
  const int b = blockIdx.x;
  const int o = threadIdx.x & 63;
  const int quad = threadIdx.x >> 6;
  __shared__ u16 wrow[64 * 64];
  __shared__ float offp[256];
  float offacc = 0.f;
#pragma unroll
  for (int ci = 0; ci < 16; ++ci) {
    const int c = quad * 16 + ci;
    const int g = c >> 1;
    const float mean = ws[WS_STATS + (b * 32 + g) * 2];
    const float rstd = ws[WS_STATS + (b * 32 + g) * 2 + 1];
    const float a = gamma[c] * rstd;
    const float d = beta[c] - mean * a;
    const float wv = phi_w[o * 64 + c];
    wrow[o * 64 + c] = f2b(wv * a * QSCALE);
    offacc += wv * d;
  }
  offp[threadIdx.x] = offacc;
  __syncthreads();
  if (quad == 0) {
    const float off = offp[o] + offp[64 + o] + offp[128 + o] + offp[192 + o];
    ws[WS_OFF + b * 64 + o] = (off + phi_b[o]) * QSCALE;
  }
  u16* wff = (u16*)(ws + WS_BF16) + BW_WFF + (size_t)b * 4096;
#pragma unroll
  for (int k = 0; k < 16; ++k) {
    const int il = threadIdx.x * 16 + k;      // [ot][ks][l][j]
    const int j = il & 7, l = (il >> 3) & 63, ks = (il >> 9) & 3, ot = il >> 11;
    const int oo = ot * 32 + (l & 31);
    const int c = ks * 16 + ((l >> 5) << 3) + j;
    wff[il] = wrow[oo * 64 + c];
  }
}

// ---- mt-loop helpers (all register indices static after inlining) ----
static __device__ __forceinline__ void loadkv(const u16* __restrict__ wb, int mt, int lane,
                                              s16x8* kf, s16x8* vf) {
#pragma unroll
  for (int ks = 0; ks < 4; ++ks)
    kf[ks] = *(const s16x8*)(wb + BW_KF + (((size_t)mt * 4 + ks) * 64 + lane) * 8);
#pragma unroll
  for (int i = 0; i < 4; ++i)
    vf[i] = *(const s16x8*)(wb + BW_VF + (((size_t)mt * 4 + i) * 64 + lane) * 8);
}
static __device__ __forceinline__ void step(const s16x8* kf, const s16x8* vf, const s16x8* q,
                                            f32x16* Y, float& Lacc) {
  f32x16 s = zero16();
#pragma unroll
  for (int ks = 0; ks < 4; ++ks)
    s = __builtin_amdgcn_mfma_f32_32x32x16_bf16(kf[ks], q[ks], s, 0, 0, 0);
  float e[16];
  float ls = 0.f;
#pragma unroll
  for (int r = 0; r < 16; ++r) { e[r] = exp2f(s[r]); ls += e[r]; }
  Lacc += ls;
  s16x8 pf0, pf1;
  d2b(e, pf0, pf1);
#pragma unroll
  for (int ct = 0; ct < 2; ++ct) {
    Y[ct] = __builtin_amdgcn_mfma_f32_32x32x16_bf16(vf[ct],     pf0, Y[ct], 0, 0, 0);
    Y[ct] = __builtin_amdgcn_mfma_f32_32x32x16_bf16(vf[2 + ct], pf1, Y[ct], 0, 0, 0);
  }
}

// ---------------- kernel 3: BARRIER-FREE, LDS-FREE, SOFTWARE-PIPELINED ----------------
// r10 post-mortem: cvt_pk cut VALU 42->34% but dur flat => VALU wasn't critical.
// Wave issues ~4k cyc of a ~31k cyc life: 87% s_waitcnt stall == ~180 loads x
// ~200cyc L2 latency SERIALIZED (each mt iter is one dep chain, loads issued at
// use). r11: explicit double-buffered kf/vf prefetch (load-use distance = 2
// steps ~800cyc) + phase-D residual-x prefetch. +~130 VGPR => (256,2); r8/r9
// showed occupancy is ~36% at both bounds, so nothing lost. Spill tripwire:
// WRITE_SIZE must stay 32768 KB.
__global__ __launch_bounds__(256, 2) void k_main(const float* __restrict__ x,
                                                 const float* __restrict__ ws,
                                                 const float* __restrict__ wz_b,
                                                 float* __restrict__ out) {
  const int b    = blockIdx.x >> 5;
  const int tile = blockIdx.x & 31;
  const int w    = threadIdx.x >> 6;
  const int lane = threadIdx.x & 63;
  const int l5 = lane & 31;
  const int hi = lane >> 5;
  const int p  = tile * 128 + w * 32 + l5;    // this lane's pixel column

  const u16* wb = (const u16*)(ws + WS_BF16);
  const float* xb = x + (size_t)b * CCH * HW;

  // ---- phase A: x -> B-frags in-register; phi = Wfold @ x + off -> Q frags ----
  s16x8 q[4];
  {
    s16x8 bx[4];
#pragma unroll
    for (int ks = 0; ks < 4; ++ks) {
      const float* xc = xb + (size_t)(ks * 16 + hi * 8) * HW + p;
      float v[8];
#pragma unroll
      for (int j = 0; j < 8; ++j) v[j] = xc[(size_t)j * HW];
      u32x4 pk = {pack2(v[0], v[1]), pack2(v[2], v[3]),
                  pack2(v[4], v[5]), pack2(v[6], v[7])};
      bx[ks] = __builtin_bit_cast(s16x8, pk);
    }
    const float* offb = ws + WS_OFF + b * 64;
#pragma unroll
    for (int ot = 0; ot < 2; ++ot) {
      f32x16 acc = zero16();
#pragma unroll
      for (int ks = 0; ks < 4; ++ks) {
        const s16x8 a = *(const s16x8*)(wb + BW_WFF + ((((size_t)b * 2 + ot) * 4 + ks) * 64 + lane) * 8);
        acc = __builtin_amdgcn_mfma_f32_32x32x16_bf16(a, bx[ks], acc, 0, 0, 0);
      }
      float e[16];
#pragma unroll
      for (int rq = 0; rq < 4; ++rq) {
        const float4 offv = *(const float4*)(offb + ot * 32 + rq * 8 + hi * 4);
#pragma unroll
        for (int rr = 0; rr < 4; ++rr) e[rq * 4 + rr] = acc[rq * 4 + rr] + ((const float*)&offv)[rr];
      }
      d2b(e, q[ot * 2], q[ot * 2 + 1]);
    }
  }

  // ---- attention: full M=512 per wave, software-pipelined, no max subtraction ----
  f32x16 Y[2];
#pragma unroll
  for (int ct = 0; ct < 2; ++ct) Y[ct] = zero16();
  float Lacc = 0.f;

  s16x8 kfA[4], vfA[4], kfB[4], vfB[4];
  loadkv(wb, 0, lane, kfA, vfA);
  loadkv(wb, 1, lane, kfB, vfB);
#pragma unroll
  for (int mt2 = 0; mt2 < 7; ++mt2) {
    step(kfA, vfA, q, Y, Lacc);
    loadkv(wb, mt2 * 2 + 2, lane, kfA, vfA);   // distance-2 prefetch
    step(kfB, vfB, q, Y, Lacc);
    loadkv(wb, mt2 * 2 + 3, lane, kfB, vfB);
  }
  step(kfA, vfA, q, Y, Lacc);
  step(kfB, vfB, q, Y, Lacc);

  const float Ltot = Lacc + __shfl_xor(Lacc, 32, 64);
  const float invL = 1.f / Ltot;

  // ---- phase D prefetch: issue residual x loads BEFORE normalize/transpose ----
  const float* xr = xb + p;
  float xres[32];
#pragma unroll
  for (int ot = 0; ot < 2; ++ot)
#pragma unroll
    for (int rq = 0; rq < 4; ++rq)
#pragma unroll
      for (int rr = 0; rr < 4; ++rr)
        xres[ot * 16 + rq * 4 + rr] = xr[(size_t)(ot * 32 + rq * 8 + hi * 4 + rr) * HW];

  // ---- Y -> wz B-frags (normalize + transpose in-register) ----
  s16x8 by[4];
#pragma unroll
  for (int ct = 0; ct < 2; ++ct) {
    float e[16];
#pragma unroll
    for (int r = 0; r < 16; ++r) e[r] = Y[ct][r] * invL;
    d2b(e, by[ct * 2], by[ct * 2 + 1]);
  }

  // ---- phase D: out = wz @ y + wz_b + x ----
  float* ob = out + (size_t)b * CCH * HW + p;
#pragma unroll
  for (int ot = 0; ot < 2; ++ot) {
    f32x16 acc = zero16();
#pragma unroll
    for (int ks = 0; ks < 4; ++ks) {
      const s16x8 a = *(const s16x8*)(wb + BW_WZF + (((size_t)ot * 4 + ks) * 64 + lane) * 8);
      acc = __builtin_amdgcn_mfma_f32_32x32x16_bf16(a, by[ks], acc, 0, 0, 0);
    }
#pragma unroll
    for (int rq = 0; rq < 4; ++rq) {
      const int obase = ot * 32 + rq * 8 + hi * 4;
      const float4 bz = *(const float4*)(wz_b + obase);
#pragma unroll
      for (int rr = 0; rr < 4; ++rr) {
        const size_t idx = (size_t)(obase + rr) * HW;
        ob[idx] = acc[rq * 4 + rr] + ((const float*)&bz)[rr] + xres[ot * 16 + rq * 4 + rr];
      }
    }
  }
}

extern "C" void kernel_launch(void* const* d_in, const int* in_sizes, int n_in,
                              void* d_out, int out_size, void* d_ws, size_t ws_size,
                              hipStream_t stream) {
  const float* x     = (const float*)d_in[0];
  const float* gamma = (const float*)d_in[1];
  const float* beta  = (const float*)d_in[2];
  const float* phi_w = (const float*)d_in[3];
  const float* phi_b = (const float*)d_in[4];
  const float* mb    = (const float*)d_in[5];
  const float* wz_w  = (const float*)d_in[6];
  const float* wz_b  = (const float*)d_in[7];
  float* out = (float*)d_out;
  float* ws  = (float*)d_ws;

  k_pre<<<1296, 256, 0, stream>>>(x, mb, wz_w, ws);
  k_prep<<<32, 256, 0, stream>>>(phi_w, phi_b, gamma, beta, ws);
  k_main<<<NFRAME * 32, 256, 0, stream>>>(x, ws, wz_b, out);
}

// Round 12
// 51.925 us; speedup vs baseline: 3.1818x; 3.1818x over previous
//
#include <hip/hip_runtime.h>
#include <hip/hip_bf16.h>

// n=2,t=16 -> 32 frames; C=64; HW=4096; M=512; 32 groups (2 ch/group).
#define NFRAME 32
#define CCH 64
#define HW 4096
#define MSLOT 512

typedef __attribute__((ext_vector_type(8))) short s16x8;    // 8 bf16 MFMA A/B frag
typedef __attribute__((ext_vector_type(16))) float f32x16;  // 32x32 MFMA C/D frag
typedef __attribute__((ext_vector_type(4))) unsigned int u32x4;
typedef __attribute__((ext_vector_type(2))) unsigned int u32x2;
typedef unsigned short u16;
typedef unsigned int u32;

// f32 workspace offsets
#define WS_STATS 0          // 1024*2 f32
#define WS_OFF   2048       // 32*64 f32
#define WS_BF16  4096       // u16 region starts here (float offset)
// u16 offsets inside bf16 region (fragment-ordered for 32x32x16 MFMA)
#define BW_KF    0                         // [16 q][4 ks][64 l][8]   QK^T A-frags (K rows m)
#define BW_VF    32768                     // [16 q][2 mh][2 ct][64 l][8] PV A-frags (V^T rows c)
#define BW_WZF   65536                     // [2 ot][4 ks][64 l][8]   wz A-frags
#define BW_WFF   69632                     // [32 b][2 ot][4 ks][64 l][8] phi A-frags

// exp2-domain scale: 1/sqrt(64) * log2(e)
#define QSCALE 0.18033688011112042f

static __device__ __forceinline__ u16 f2b(float f) {
  __hip_bfloat16 h = __float2bfloat16(f);
  return *reinterpret_cast<u16*>(&h);
}
// bf16 pair pack via v_cvt_pk_bf16_f32 (lane-local pure VALU op; RNE; safe as
// non-volatile asm — r5's miscompile was CROSS-LANE asm, this is arithmetic).
static __device__ __forceinline__ u32 pack2(float a, float b) {
  u32 r;
  asm("v_cvt_pk_bf16_f32 %0, %1, %2" : "=v"(r) : "v"(a), "v"(b));
  return r;
}
static __device__ __forceinline__ f32x16 zero16() {
  f32x16 z;
#pragma unroll
  for (int r = 0; r < 16; ++r) z[r] = 0.f;
  return z;
}
// D-layout -> B-frag transpose (verified r6): input 16 f32 regs e[] holding
// D[row rmap(r,hi)][col l5]; output B-frags f0 (k=0..15), f1 (k=16..31),
// lane row = l5. cvt_pk packs + convergent permlane32_swap builtin.
static __device__ __forceinline__ void d2b(const float* e, s16x8& f0, s16x8& f1) {
#pragma unroll
  for (int mh = 0; mh < 2; ++mh) {
    const u32 P0 = pack2(e[mh * 8 + 0], e[mh * 8 + 1]);
    const u32 P1 = pack2(e[mh * 8 + 2], e[mh * 8 + 3]);
    const u32 Q0 = pack2(e[mh * 8 + 4], e[mh * 8 + 5]);
    const u32 Q1 = pack2(e[mh * 8 + 6], e[mh * 8 + 7]);
    const u32x2 s0 = __builtin_amdgcn_permlane32_swap(P0, Q0, false, false);
    const u32x2 s1 = __builtin_amdgcn_permlane32_swap(P1, Q1, false, false);
    u32x4 bw = {s0[0], s1[0], s0[1], s1[1]};
    if (mh == 0) f0 = __builtin_bit_cast(s16x8, bw);
    else         f1 = __builtin_bit_cast(s16x8, bw);
  }
}

// ---------------- kernel 1: GroupNorm stats (blocks 0..1023) + mb/wz frag tables (1024..1295) ----------------
__global__ __launch_bounds__(256) void k_pre(const float* __restrict__ x,
                                             const float* __restrict__ mb,
                                             const float* __restrict__ wz_w,
                                             float* __restrict__ ws) {
  if (blockIdx.x < 1024) {
    const int bg = blockIdx.x;
    const float4* xp = (const float4*)(x + (size_t)bg * 8192);
    const int t = threadIdx.x;
    float s = 0.f, s2 = 0.f;
#pragma unroll
    for (int i = 0; i < 8; ++i) {
      float4 v = xp[t + i * 256];
      s  += v.x + v.y + v.z + v.w;
      s2 += v.x * v.x + v.y * v.y + v.z * v.z + v.w * v.w;
    }
    for (int off = 32; off; off >>= 1) {
      s  += __shfl_down(s,  off, 64);
      s2 += __shfl_down(s2, off, 64);
    }
    __shared__ float ls[8];
    const int wid = t >> 6;
    if ((t & 63) == 0) { ls[wid * 2] = s; ls[wid * 2 + 1] = s2; }
    __syncthreads();
    if (t == 0) {
      float S = 0.f, S2 = 0.f;
#pragma unroll
      for (int w = 0; w < 4; ++w) { S += ls[w * 2]; S2 += ls[w * 2 + 1]; }
      float mean = S * (1.f / 8192.f);
      float var  = S2 * (1.f / 8192.f) - mean * mean;
      float rstd = rsqrtf(var + 1e-6f);
      ws[WS_STATS + bg * 2]     = mean;
      ws[WS_STATS + bg * 2 + 1] = rstd;
    }
    return;
  }
  // fragment tables
  u16* wbw = (u16*)(ws + WS_BF16);
  const int i = (blockIdx.x - 1024) * 256 + threadIdx.x;
  if (i < 32768) {                           // KF[q][ks][l][j]: m=q*32+(l&31), c=ks*16+(l>>5)*8+j
    const int j = i & 7, l = (i >> 3) & 63, ks = (i >> 9) & 3, q = i >> 11;
    const int c = ks * 16 + ((l >> 5) << 3) + j;
    const int m = q * 32 + (l & 31);
    wbw[BW_KF + i] = f2b(mb[c * MSLOT + m]);
  } else if (i < 65536) {                    // VF[q][mh][ct][l][j]: c=ct*32+(l&31), m=q*32+mh*16+(l>>5)*8+j
    const int i2 = i - 32768;
    const int j = i2 & 7, l = (i2 >> 3) & 63, ct = (i2 >> 9) & 1, mh = (i2 >> 10) & 1, q = i2 >> 11;
    const int c = ct * 32 + (l & 31);
    const int m = q * 32 + mh * 16 + ((l >> 5) << 3) + j;
    wbw[BW_VF + i2] = f2b(mb[c * MSLOT + m]);
  } else {                                   // WZF[ot][ks][l][j]: o=ot*32+(l&31), c=ks*16+(l>>5)*8+j
    const int i3 = i - 65536;
    const int j = i3 & 7, l = (i3 >> 3) & 63, ks = (i3 >> 9) & 3, ot = i3 >> 11;
    const int o = ot * 32 + (l & 31);
    const int c = ks * 16 + ((l >> 5) << 3) + j;
    wbw[BW_WZF + i3] = f2b(wz_w[o * 64 + c]);
  }
}

// ---------------- kernel 2: fold GN + scale into bf16 phi weights, emit frag-ordered WFF ----------------
__global__ __launch_bounds__(256) void k_prep(const float* __restrict__ phi_w,
                                              const float* __restrict__ phi_b,
                                              const float* __restrict__ gamma,
                                              const float* __restrict__ beta,
                                              float* __restrict__ ws) {
  const int b = blockIdx.x;
  const int o = threadIdx.x & 63;
  const int quad = threadIdx.x >> 6;
  __shared__ u16 wrow[64 * 64];
  __shared__ float offp[256];
  float offacc = 0.f;
#pragma unroll
  for (int ci = 0; ci < 16; ++ci) {
    const int c = quad * 16 + ci;
    const int g = c >> 1;
    const float mean = ws[WS_STATS + (b * 32 + g) * 2];
    const float rstd = ws[WS_STATS + (b * 32 + g) * 2 + 1];
    const float a = gamma[c] * rstd;
    const float d = beta[c] - mean * a;
    const float wv = phi_w[o * 64 + c];
    wrow[o * 64 + c] = f2b(wv * a * QSCALE);
    offacc += wv * d;
  }
  offp[threadIdx.x] = offacc;
  __syncthreads();
  if (quad == 0) {
    const float off = offp[o] + offp[64 + o] + offp[128 + o] + offp[192 + o];
    ws[WS_OFF + b * 64 + o] = (off + phi_b[o]) * QSCALE;
  }
  u16* wff = (u16*)(ws + WS_BF16) + BW_WFF + (size_t)b * 4096;
#pragma unroll
  for (int k = 0; k < 16; ++k) {
    const int il = threadIdx.x * 16 + k;      // [ot][ks][l][j]
    const int j = il & 7, l = (il >> 3) & 63, ks = (il >> 9) & 3, ot = il >> 11;
    const int oo = ot * 32 + (l & 31);
    const int c = ks * 16 + ((l >> 5) << 3) + j;
    wff[il] = wrow[oo * 64 + c];
  }
}

// ---------------- kernel 3: BARRIER-FREE, LDS-FREE; wave = 64 pixels (2 B-columns) ----------------
// r11 post-mortem: manual dbuf+xres prefetch overflowed the 128 arch-VGPR half
// of the unified file (VGPR_Count=128, WRITE 223MB spills) -> reverted.
// r12: halve K/V L2 traffic instead — each wave owns TWO 32-pixel B-columns,
// sharing every kf/vf load across both (K/V table read per 64 px, not 32).
// Loads/pixel -30%, MFMA/load 2x. Grid 512 blocks x 4 waves = 2 blocks/CU
// fully resident. Arch-VGPR live set in mt loop ~110 (<128): q 32, kf/vf 32,
// e 16, pf 8, addr ~20. Y[2][2]+s stay in AGPRs. Spill tripwire: WRITE_SIZE
// must stay 32768 KB, FETCH ~30MB.
__global__ __launch_bounds__(256, 2) void k_main(const float* __restrict__ x,
                                                 const float* __restrict__ ws,
                                                 const float* __restrict__ wz_b,
                                                 float* __restrict__ out) {
  const int b    = blockIdx.x >> 4;
  const int tile = blockIdx.x & 15;
  const int w    = threadIdx.x >> 6;
  const int lane = threadIdx.x & 63;
  const int l5 = lane & 31;
  const int hi = lane >> 5;
  const int pbase = tile * 256 + w * 64 + l5;   // pixel column for pt=0; pt=1 adds 32

  const u16* wb = (const u16*)(ws + WS_BF16);
  const float* xb = x + (size_t)b * CCH * HW;

  // ---- phase A: x -> B-frags; phi = Wfold @ x + off -> Q frags (per pixel-tile) ----
  s16x8 q[2][4];
#pragma unroll
  for (int pt = 0; pt < 2; ++pt) {
    const int p = pbase + pt * 32;
    s16x8 bx[4];
#pragma unroll
    for (int ks = 0; ks < 4; ++ks) {
      const float* xc = xb + (size_t)(ks * 16 + hi * 8) * HW + p;
      float v[8];
#pragma unroll
      for (int j = 0; j < 8; ++j) v[j] = xc[(size_t)j * HW];
      u32x4 pk = {pack2(v[0], v[1]), pack2(v[2], v[3]),
                  pack2(v[4], v[5]), pack2(v[6], v[7])};
      bx[ks] = __builtin_bit_cast(s16x8, pk);
    }
    const float* offb = ws + WS_OFF + b * 64;
#pragma unroll
    for (int ot = 0; ot < 2; ++ot) {
      f32x16 acc = zero16();
#pragma unroll
      for (int ks = 0; ks < 4; ++ks) {
        const s16x8 a = *(const s16x8*)(wb + BW_WFF + ((((size_t)b * 2 + ot) * 4 + ks) * 64 + lane) * 8);
        acc = __builtin_amdgcn_mfma_f32_32x32x16_bf16(a, bx[ks], acc, 0, 0, 0);
      }
      float e[16];
#pragma unroll
      for (int rq = 0; rq < 4; ++rq) {
        const float4 offv = *(const float4*)(offb + ot * 32 + rq * 8 + hi * 4);
#pragma unroll
        for (int rr = 0; rr < 4; ++rr) e[rq * 4 + rr] = acc[rq * 4 + rr] + ((const float*)&offv)[rr];
      }
      d2b(e, q[pt][ot * 2], q[pt][ot * 2 + 1]);
    }
  }

  // ---- attention: full M=512 per wave, kf/vf shared across both pixel-tiles ----
  f32x16 Y[2][2];   // [pt][ct]
#pragma unroll
  for (int pt = 0; pt < 2; ++pt)
#pragma unroll
    for (int ct = 0; ct < 2; ++ct) Y[pt][ct] = zero16();
  float Lacc[2] = {0.f, 0.f};

#pragma unroll 2
  for (int mt = 0; mt < 16; ++mt) {
    s16x8 kf[4], vf[4];
#pragma unroll
    for (int ks = 0; ks < 4; ++ks)
      kf[ks] = *(const s16x8*)(wb + BW_KF + (((size_t)mt * 4 + ks) * 64 + lane) * 8);
#pragma unroll
    for (int i = 0; i < 4; ++i)
      vf[i] = *(const s16x8*)(wb + BW_VF + (((size_t)mt * 4 + i) * 64 + lane) * 8);

#pragma unroll
    for (int pt = 0; pt < 2; ++pt) {
      f32x16 s = zero16();
#pragma unroll
      for (int ks = 0; ks < 4; ++ks)
        s = __builtin_amdgcn_mfma_f32_32x32x16_bf16(kf[ks], q[pt][ks], s, 0, 0, 0);
      float e[16];
      float ls = 0.f;
#pragma unroll
      for (int r = 0; r < 16; ++r) { e[r] = exp2f(s[r]); ls += e[r]; }
      Lacc[pt] += ls;
      s16x8 pf0, pf1;
      d2b(e, pf0, pf1);
#pragma unroll
      for (int ct = 0; ct < 2; ++ct) {
        Y[pt][ct] = __builtin_amdgcn_mfma_f32_32x32x16_bf16(vf[ct],     pf0, Y[pt][ct], 0, 0, 0);
        Y[pt][ct] = __builtin_amdgcn_mfma_f32_32x32x16_bf16(vf[2 + ct], pf1, Y[pt][ct], 0, 0, 0);
      }
    }
  }

  // ---- finish: per pixel-tile normalize, transpose, wz, residual, store ----
#pragma unroll
  for (int pt = 0; pt < 2; ++pt) {
    const int p = pbase + pt * 32;
    const float Ltot = Lacc[pt] + __shfl_xor(Lacc[pt], 32, 64);
    const float invL = 1.f / Ltot;
    s16x8 by[4];
#pragma unroll
    for (int ct = 0; ct < 2; ++ct) {
      float e[16];
#pragma unroll
      for (int r = 0; r < 16; ++r) e[r] = Y[pt][ct][r] * invL;
      d2b(e, by[ct * 2], by[ct * 2 + 1]);
    }
    const float* xr = xb + p;
    float* ob = out + (size_t)b * CCH * HW + p;
#pragma unroll
    for (int ot = 0; ot < 2; ++ot) {
      f32x16 acc = zero16();
#pragma unroll
      for (int ks = 0; ks < 4; ++ks) {
        const s16x8 a = *(const s16x8*)(wb + BW_WZF + (((size_t)ot * 4 + ks) * 64 + lane) * 8);
        acc = __builtin_amdgcn_mfma_f32_32x32x16_bf16(a, by[ks], acc, 0, 0, 0);
      }
#pragma unroll
      for (int rq = 0; rq < 4; ++rq) {
        const int obase = ot * 32 + rq * 8 + hi * 4;
        const float4 bz = *(const float4*)(wz_b + obase);
#pragma unroll
        for (int rr = 0; rr < 4; ++rr) {
          const size_t idx = (size_t)(obase + rr) * HW;
          ob[idx] = acc[rq * 4 + rr] + ((const float*)&bz)[rr] + xr[idx];
        }
      }
    }
  }
}

extern "C" void kernel_launch(void* const* d_in, const int* in_sizes, int n_in,
                              void* d_out, int out_size, void* d_ws, size_t ws_size,
                              hipStream_t stream) {
  const float* x     = (const float*)d_in[0];
  const float* gamma = (const float*)d_in[1];
  const float* beta  = (const float*)d_in[2];
  const float* phi_w = (const float*)d_in[3];
  const float* phi_b = (const float*)d_in[4];
  const float* mb    = (const float*)d_in[5];
  const float* wz_w  = (const float*)d_in[6];
  const float* wz_b  = (const float*)d_in[7];
  float* out = (float*)d_out;
  float* ws  = (float*)d_ws;

  k_pre<<<1296, 256, 0, stream>>>(x, mb, wz_w, ws);
  k_prep<<<32, 256, 0, stream>>>(phi_w, phi_b, gamma, beta, ws);
  k_main<<<NFRAME * 16, 256, 0, stream>>>(x, ws, wz_b, out);
}

// Round 13
// 50.393 us; speedup vs baseline: 3.2785x; 1.0304x over previous
//
#include <hip/hip_runtime.h>
#include <hip/hip_bf16.h>

// n=2,t=16 -> 32 frames; C=64; HW=4096; M=512; 32 groups (2 ch/group).
#define NFRAME 32
#define CCH 64
#define HW 4096
#define MSLOT 512

typedef __attribute__((ext_vector_type(8))) short s16x8;    // 8 bf16 MFMA A/B frag
typedef __attribute__((ext_vector_type(16))) float f32x16;  // 32x32 MFMA C/D frag
typedef __attribute__((ext_vector_type(4))) unsigned int u32x4;
typedef __attribute__((ext_vector_type(2))) unsigned int u32x2;
typedef unsigned short u16;
typedef unsigned int u32;

// f32 workspace offsets
#define WS_STATS 0          // 1024*2 f32
#define WS_OFF   2048       // 32*64 f32
#define WS_BF16  4096       // u16 region starts here (float offset)
// u16 offsets inside bf16 region
#define BW_KV    0                         // [16 mt][8 f][512]  f=0..3 KF ks, f=4..7 VF (mh*2+ct)
#define BW_WZF   65536                     // [2 ot][4 ks][64 l][8]   wz A-frags
#define BW_WFF   69632                     // [32 b][2 ot][4 ks][64 l][8] phi A-frags

// exp2-domain scale: 1/sqrt(64) * log2(e)
#define QSCALE 0.18033688011112042f

static __device__ __forceinline__ u16 f2b(float f) {
  __hip_bfloat16 h = __float2bfloat16(f);
  return *reinterpret_cast<u16*>(&h);
}
// bf16 pair pack via v_cvt_pk_bf16_f32 (lane-local pure VALU op; RNE; safe as
// non-volatile asm — r5's miscompile was CROSS-LANE asm, this is arithmetic).
static __device__ __forceinline__ u32 pack2(float a, float b) {
  u32 r;
  asm("v_cvt_pk_bf16_f32 %0, %1, %2" : "=v"(r) : "v"(a), "v"(b));
  return r;
}
static __device__ __forceinline__ f32x16 zero16() {
  f32x16 z;
#pragma unroll
  for (int r = 0; r < 16; ++r) z[r] = 0.f;
  return z;
}
// D-layout -> B-frag transpose (verified r6): input 16 f32 regs e[] holding
// D[row rmap(r,hi)][col l5]; output B-frags f0 (k=0..15), f1 (k=16..31),
// lane row = l5. cvt_pk packs + convergent permlane32_swap builtin.
static __device__ __forceinline__ void d2b(const float* e, s16x8& f0, s16x8& f1) {
#pragma unroll
  for (int mh = 0; mh < 2; ++mh) {
    const u32 P0 = pack2(e[mh * 8 + 0], e[mh * 8 + 1]);
    const u32 P1 = pack2(e[mh * 8 + 2], e[mh * 8 + 3]);
    const u32 Q0 = pack2(e[mh * 8 + 4], e[mh * 8 + 5]);
    const u32 Q1 = pack2(e[mh * 8 + 6], e[mh * 8 + 7]);
    const u32x2 s0 = __builtin_amdgcn_permlane32_swap(P0, Q0, false, false);
    const u32x2 s1 = __builtin_amdgcn_permlane32_swap(P1, Q1, false, false);
    u32x4 bw = {s0[0], s1[0], s0[1], s1[1]};
    if (mh == 0) f0 = __builtin_bit_cast(s16x8, bw);
    else         f1 = __builtin_bit_cast(s16x8, bw);
  }
}

// ---------------- kernel 1: GroupNorm stats (blocks 0..1023) + KV/wz frag tables (1024..1295) ----------------
__global__ __launch_bounds__(256) void k_pre(const float* __restrict__ x,
                                             const float* __restrict__ mb,
                                             const float* __restrict__ wz_w,
                                             float* __restrict__ ws) {
  if (blockIdx.x < 1024) {
    const int bg = blockIdx.x;
    const float4* xp = (const float4*)(x + (size_t)bg * 8192);
    const int t = threadIdx.x;
    float s = 0.f, s2 = 0.f;
#pragma unroll
    for (int i = 0; i < 8; ++i) {
      float4 v = xp[t + i * 256];
      s  += v.x + v.y + v.z + v.w;
      s2 += v.x * v.x + v.y * v.y + v.z * v.z + v.w * v.w;
    }
    for (int off = 32; off; off >>= 1) {
      s  += __shfl_down(s,  off, 64);
      s2 += __shfl_down(s2, off, 64);
    }
    __shared__ float ls[8];
    const int wid = t >> 6;
    if ((t & 63) == 0) { ls[wid * 2] = s; ls[wid * 2 + 1] = s2; }
    __syncthreads();
    if (t == 0) {
      float S = 0.f, S2 = 0.f;
#pragma unroll
      for (int w = 0; w < 4; ++w) { S += ls[w * 2]; S2 += ls[w * 2 + 1]; }
      float mean = S * (1.f / 8192.f);
      float var  = S2 * (1.f / 8192.f) - mean * mean;
      float rstd = rsqrtf(var + 1e-6f);
      ws[WS_STATS + bg * 2]     = mean;
      ws[WS_STATS + bg * 2 + 1] = rstd;
    }
    return;
  }
  // fragment tables
  u16* wbw = (u16*)(ws + WS_BF16);
  const int i = (blockIdx.x - 1024) * 256 + threadIdx.x;
  if (i < 65536) {
    // KV[mt][f][l][j]: f<4 -> KF ks=f: c=f*16+(l>>5)*8+j, m=mt*32+(l&31)
    //                  f>=4 -> VF idx=f-4 (mh=idx>>1, ct=idx&1):
    //                          c=ct*32+(l&31), m=mt*32+mh*16+(l>>5)*8+j
    const int j = i & 7, l = (i >> 3) & 63, f = (i >> 9) & 7, mt = i >> 12;
    float v;
    if (f < 4) {
      const int c = f * 16 + ((l >> 5) << 3) + j;
      const int m = mt * 32 + (l & 31);
      v = mb[c * MSLOT + m];
    } else {
      const int idx = f - 4;
      const int c = (idx & 1) * 32 + (l & 31);
      const int m = mt * 32 + (idx >> 1) * 16 + ((l >> 5) << 3) + j;
      v = mb[c * MSLOT + m];
    }
    wbw[BW_KV + i] = f2b(v);
  } else {                                   // WZF[ot][ks][l][j]: o=ot*32+(l&31), c=ks*16+(l>>5)*8+j
    const int i3 = i - 65536;
    const int j = i3 & 7, l = (i3 >> 3) & 63, ks = (i3 >> 9) & 3, ot = i3 >> 11;
    const int o = ot * 32 + (l & 31);
    const int c = ks * 16 + ((l >> 5) << 3) + j;
    wbw[BW_WZF + i3] = f2b(wz_w[o * 64 + c]);
  }
}

// ---------------- kernel 2: fold GN + scale into bf16 phi weights, emit frag-ordered WFF ----------------
__global__ __launch_bounds__(256) void k_prep(const float* __restrict__ phi_w,
                                              const float* __restrict__ phi_b,
                                              const float* __restrict__ gamma,
                                              const float* __restrict__ beta,
                                              float* __restrict__ ws) {
  const int b = blockIdx.x;
  const int o = threadIdx.x & 63;
  const int quad = threadIdx.x >> 6;
  __shared__ u16 wrow[64 * 64];
  __shared__ float offp[256];
  float offacc = 0.f;
#pragma unroll
  for (int ci = 0; ci < 16; ++ci) {
    const int c = quad * 16 + ci;
    const int g = c >> 1;
    const float mean = ws[WS_STATS + (b * 32 + g) * 2];
    const float rstd = ws[WS_STATS + (b * 32 + g) * 2 + 1];
    const float a = gamma[c] * rstd;
    const float d = beta[c] - mean * a;
    const float wv = phi_w[o * 64 + c];
    wrow[o * 64 + c] = f2b(wv * a * QSCALE);
    offacc += wv * d;
  }
  offp[threadIdx.x] = offacc;
  __syncthreads();
  if (quad == 0) {
    const float off = offp[o] + offp[64 + o] + offp[128 + o] + offp[192 + o];
    ws[WS_OFF + b * 64 + o] = (off + phi_b[o]) * QSCALE;
  }
  u16* wff = (u16*)(ws + WS_BF16) + BW_WFF + (size_t)b * 4096;
#pragma unroll
  for (int k = 0; k < 16; ++k) {
    const int il = threadIdx.x * 16 + k;      // [ot][ks][l][j]
    const int j = il & 7, l = (il >> 3) & 63, ks = (il >> 9) & 3, ot = il >> 11;
    const int oo = ot * 32 + (l & 31);
    const int c = ks * 16 + ((l >> 5) << 3) + j;
    wff[il] = wrow[oo * 64 + c];
  }
}

// ---------------- kernel 3: wave = 64 px; K/V staged through LDS once per block ----------------
// r12 post-mortem: ~2.9k cyc/iter vs ~1k issue — gap is per-wave L2 latency on
// K/V loads that all 4 waves duplicate. r13: KV[mt][8][1KB] is already linear
// lane*16B -> global_load_lds width=16 stages next tile (each wave 2 frags,
// 8KB dbuf, 16KB LDS); compute reads ds_read_b128; ONE __syncthreads/iter whose
// vmcnt drain lands after ~1k cyc of compute (issue-early/drain-late, zero VGPR
// cost). K/V L2 traffic /4. Compute body identical to r12.
__global__ __launch_bounds__(256, 2) void k_main(const float* __restrict__ x,
                                                 const float* __restrict__ ws,
                                                 const float* __restrict__ wz_b,
                                                 float* __restrict__ out) {
  const int b    = blockIdx.x >> 4;
  const int tile = blockIdx.x & 15;
  const int w    = threadIdx.x >> 6;
  const int lane = threadIdx.x & 63;
  const int l5 = lane & 31;
  const int hi = lane >> 5;
  const int pbase = tile * 256 + w * 64 + l5;   // pixel column for pt=0; pt=1 adds 32

  const u16* wb = (const u16*)(ws + WS_BF16);
  const float* xb = x + (size_t)b * CCH * HW;

  __shared__ __align__(16) u16 kv[2][8][512];   // 16KB double-buffered K/V tile

  // stage 8KB tile mt into buffer nb: wave w moves fragments w*2, w*2+1
#define STAGE(mt_, nb_)                                                          \
  {                                                                              \
    _Pragma("unroll")                                                            \
    for (int k = 0; k < 2; ++k) {                                                \
      const int f = w * 2 + k;                                                   \
      const u16* src = wb + BW_KV + ((size_t)(mt_) * 8 + f) * 512 + lane * 8;    \
      __builtin_amdgcn_global_load_lds(                                          \
          (const __attribute__((address_space(1))) void*)src,                    \
          (__attribute__((address_space(3))) void*)&kv[nb_][f][0], 16, 0, 0);    \
    }                                                                            \
  }

  STAGE(0, 0);   // prologue: tile 0 -> buf 0 (drained by first loop barrier path)

  // ---- phase A: x -> B-frags; phi = Wfold @ x + off -> Q frags (per pixel-tile) ----
  s16x8 q[2][4];
#pragma unroll
  for (int pt = 0; pt < 2; ++pt) {
    const int p = pbase + pt * 32;
    s16x8 bx[4];
#pragma unroll
    for (int ks = 0; ks < 4; ++ks) {
      const float* xc = xb + (size_t)(ks * 16 + hi * 8) * HW + p;
      float v[8];
#pragma unroll
      for (int j = 0; j < 8; ++j) v[j] = xc[(size_t)j * HW];
      u32x4 pk = {pack2(v[0], v[1]), pack2(v[2], v[3]),
                  pack2(v[4], v[5]), pack2(v[6], v[7])};
      bx[ks] = __builtin_bit_cast(s16x8, pk);
    }
    const float* offb = ws + WS_OFF + b * 64;
#pragma unroll
    for (int ot = 0; ot < 2; ++ot) {
      f32x16 acc = zero16();
#pragma unroll
      for (int ks = 0; ks < 4; ++ks) {
        const s16x8 a = *(const s16x8*)(wb + BW_WFF + ((((size_t)b * 2 + ot) * 4 + ks) * 64 + lane) * 8);
        acc = __builtin_amdgcn_mfma_f32_32x32x16_bf16(a, bx[ks], acc, 0, 0, 0);
      }
      float e[16];
#pragma unroll
      for (int rq = 0; rq < 4; ++rq) {
        const float4 offv = *(const float4*)(offb + ot * 32 + rq * 8 + hi * 4);
#pragma unroll
        for (int rr = 0; rr < 4; ++rr) e[rq * 4 + rr] = acc[rq * 4 + rr] + ((const float*)&offv)[rr];
      }
      d2b(e, q[pt][ot * 2], q[pt][ot * 2 + 1]);
    }
  }

  // ---- attention: full M=512 per wave; K/V from LDS, dbuf-staged ----
  f32x16 Y[2][2];   // [pt][ct]
#pragma unroll
  for (int pt = 0; pt < 2; ++pt)
#pragma unroll
    for (int ct = 0; ct < 2; ++ct) Y[pt][ct] = zero16();
  float Lacc[2] = {0.f, 0.f};

  __syncthreads();   // stage(0) complete, phase-A LDS-free so no other hazard

#pragma unroll 2
  for (int mt = 0; mt < 16; ++mt) {
    const int cb = mt & 1;
    if (mt < 15) STAGE(mt + 1, cb ^ 1);   // issue next tile early; drains at barrier below

    s16x8 kf[4], vf[4];
#pragma unroll
    for (int ks = 0; ks < 4; ++ks)
      kf[ks] = *(const s16x8*)&kv[cb][ks][(size_t)lane * 8];
#pragma unroll
    for (int i = 0; i < 4; ++i)
      vf[i] = *(const s16x8*)&kv[cb][4 + i][(size_t)lane * 8];

#pragma unroll
    for (int pt = 0; pt < 2; ++pt) {
      f32x16 s = zero16();
#pragma unroll
      for (int ks = 0; ks < 4; ++ks)
        s = __builtin_amdgcn_mfma_f32_32x32x16_bf16(kf[ks], q[pt][ks], s, 0, 0, 0);
      float e[16];
      float ls = 0.f;
#pragma unroll
      for (int r = 0; r < 16; ++r) { e[r] = exp2f(s[r]); ls += e[r]; }
      Lacc[pt] += ls;
      s16x8 pf0, pf1;
      d2b(e, pf0, pf1);
#pragma unroll
      for (int ct = 0; ct < 2; ++ct) {
        Y[pt][ct] = __builtin_amdgcn_mfma_f32_32x32x16_bf16(vf[ct],     pf0, Y[pt][ct], 0, 0, 0);
        Y[pt][ct] = __builtin_amdgcn_mfma_f32_32x32x16_bf16(vf[2 + ct], pf1, Y[pt][ct], 0, 0, 0);
      }
    }
    __syncthreads();  // drains next-tile stage (flew during compute) + guards buf reuse
  }

  // ---- finish: per pixel-tile normalize, transpose, wz, residual, store ----
#pragma unroll
  for (int pt = 0; pt < 2; ++pt) {
    const int p = pbase + pt * 32;
    const float Ltot = Lacc[pt] + __shfl_xor(Lacc[pt], 32, 64);
    const float invL = 1.f / Ltot;
    s16x8 by[4];
#pragma unroll
    for (int ct = 0; ct < 2; ++ct) {
      float e[16];
#pragma unroll
      for (int r = 0; r < 16; ++r) e[r] = Y[pt][ct][r] * invL;
      d2b(e, by[ct * 2], by[ct * 2 + 1]);
    }
    const float* xr = xb + p;
    float* ob = out + (size_t)b * CCH * HW + p;
#pragma unroll
    for (int ot = 0; ot < 2; ++ot) {
      f32x16 acc = zero16();
#pragma unroll
      for (int ks = 0; ks < 4; ++ks) {
        const s16x8 a = *(const s16x8*)(wb + BW_WZF + (((size_t)ot * 4 + ks) * 64 + lane) * 8);
        acc = __builtin_amdgcn_mfma_f32_32x32x16_bf16(a, by[ks], acc, 0, 0, 0);
      }
#pragma unroll
      for (int rq = 0; rq < 4; ++rq) {
        const int obase = ot * 32 + rq * 8 + hi * 4;
        const float4 bz = *(const float4*)(wz_b + obase);
#pragma unroll
        for (int rr = 0; rr < 4; ++rr) {
          const size_t idx = (size_t)(obase + rr) * HW;
          ob[idx] = acc[rq * 4 + rr] + ((const float*)&bz)[rr] + xr[idx];
        }
      }
    }
  }
#undef STAGE
}

extern "C" void kernel_launch(void* const* d_in, const int* in_sizes, int n_in,
                              void* d_out, int out_size, void* d_ws, size_t ws_size,
                              hipStream_t stream) {
  const float* x     = (const float*)d_in[0];
  const float* gamma = (const float*)d_in[1];
  const float* beta  = (const float*)d_in[2];
  const float* phi_w = (const float*)d_in[3];
  const float* phi_b = (const float*)d_in[4];
  const float* mb    = (const float*)d_in[5];
  const float* wz_w  = (const float*)d_in[6];
  const float* wz_b  = (const float*)d_in[7];
  float* out = (float*)d_out;
  float* ws  = (float*)d_ws;

  k_pre<<<1296, 256, 0, stream>>>(x, mb, wz_w, ws);
  k_prep<<<32, 256, 0, stream>>>(phi_w, phi_b, gamma, beta, ws);
  k_main<<<NFRAME * 16, 256, 0, stream>>>(x, ws, wz_b, out);
}

// Round 14
// 48.986 us; speedup vs baseline: 3.3727x; 1.0287x over previous
//
#include <hip/hip_runtime.h>
#include <hip/hip_bf16.h>

// n=2,t=16 -> 32 frames; C=64; HW=4096; M=512; 32 groups (2 ch/group).
#define NFRAME 32
#define CCH 64
#define HW 4096
#define MSLOT 512

typedef __attribute__((ext_vector_type(8))) short s16x8;    // 8 bf16 MFMA A/B frag
typedef __attribute__((ext_vector_type(16))) float f32x16;  // 32x32 MFMA C/D frag
typedef __attribute__((ext_vector_type(4))) unsigned int u32x4;
typedef __attribute__((ext_vector_type(2))) unsigned int u32x2;
typedef unsigned short u16;
typedef unsigned int u32;

// f32 workspace offsets
#define WS_STATS 0          // 1024*2 f32
#define WS_OFF   2048       // 32*64 f32
#define WS_BF16  4096       // u16 region starts here (float offset)
// u16 offsets inside bf16 region
#define BW_KV    0                         // [16 mt][8 f][512]  f=0..3 KF ks, f=4..7 VF (mh*2+ct)
#define BW_WZF   65536                     // [2 ot][4 ks][64 l][8]   wz A-frags
#define BW_WFF   69632                     // [32 b][2 ot][4 ks][64 l][8] phi A-frags

// exp2-domain scale: 1/sqrt(64) * log2(e)
#define QSCALE 0.18033688011112042f

static __device__ __forceinline__ u16 f2b(float f) {
  __hip_bfloat16 h = __float2bfloat16(f);
  return *reinterpret_cast<u16*>(&h);
}
// bf16 pair pack via v_cvt_pk_bf16_f32 (lane-local pure VALU op; RNE; safe as
// non-volatile asm — r5's miscompile was CROSS-LANE asm, this is arithmetic).
static __device__ __forceinline__ u32 pack2(float a, float b) {
  u32 r;
  asm("v_cvt_pk_bf16_f32 %0, %1, %2" : "=v"(r) : "v"(a), "v"(b));
  return r;
}
static __device__ __forceinline__ f32x16 zero16() {
  f32x16 z;
#pragma unroll
  for (int r = 0; r < 16; ++r) z[r] = 0.f;
  return z;
}
// D-layout -> B-frag transpose (verified r6): input 16 f32 regs e[] holding
// D[row rmap(r,hi)][col l5]; output B-frags f0 (k=0..15), f1 (k=16..31),
// lane row = l5. cvt_pk packs + convergent permlane32_swap builtin.
static __device__ __forceinline__ void d2b(const float* e, s16x8& f0, s16x8& f1) {
#pragma unroll
  for (int mh = 0; mh < 2; ++mh) {
    const u32 P0 = pack2(e[mh * 8 + 0], e[mh * 8 + 1]);
    const u32 P1 = pack2(e[mh * 8 + 2], e[mh * 8 + 3]);
    const u32 Q0 = pack2(e[mh * 8 + 4], e[mh * 8 + 5]);
    const u32 Q1 = pack2(e[mh * 8 + 6], e[mh * 8 + 7]);
    const u32x2 s0 = __builtin_amdgcn_permlane32_swap(P0, Q0, false, false);
    const u32x2 s1 = __builtin_amdgcn_permlane32_swap(P1, Q1, false, false);
    u32x4 bw = {s0[0], s1[0], s0[1], s1[1]};
    if (mh == 0) f0 = __builtin_bit_cast(s16x8, bw);
    else         f1 = __builtin_bit_cast(s16x8, bw);
  }
}

// ---------------- kernel 1: GroupNorm stats (blocks 0..1023) + KV/wz frag tables (1024..1295) ----------------
__global__ __launch_bounds__(256) void k_pre(const float* __restrict__ x,
                                             const float* __restrict__ mb,
                                             const float* __restrict__ wz_w,
                                             float* __restrict__ ws) {
  if (blockIdx.x < 1024) {
    const int bg = blockIdx.x;
    const float4* xp = (const float4*)(x + (size_t)bg * 8192);
    const int t = threadIdx.x;
    float s = 0.f, s2 = 0.f;
#pragma unroll
    for (int i = 0; i < 8; ++i) {
      float4 v = xp[t + i * 256];
      s  += v.x + v.y + v.z + v.w;
      s2 += v.x * v.x + v.y * v.y + v.z * v.z + v.w * v.w;
    }
    for (int off = 32; off; off >>= 1) {
      s  += __shfl_down(s,  off, 64);
      s2 += __shfl_down(s2, off, 64);
    }
    __shared__ float ls[8];
    const int wid = t >> 6;
    if ((t & 63) == 0) { ls[wid * 2] = s; ls[wid * 2 + 1] = s2; }
    __syncthreads();
    if (t == 0) {
      float S = 0.f, S2 = 0.f;
#pragma unroll
      for (int w = 0; w < 4; ++w) { S += ls[w * 2]; S2 += ls[w * 2 + 1]; }
      float mean = S * (1.f / 8192.f);
      float var  = S2 * (1.f / 8192.f) - mean * mean;
      float rstd = rsqrtf(var + 1e-6f);
      ws[WS_STATS + bg * 2]     = mean;
      ws[WS_STATS + bg * 2 + 1] = rstd;
    }
    return;
  }
  // fragment tables
  u16* wbw = (u16*)(ws + WS_BF16);
  const int i = (blockIdx.x - 1024) * 256 + threadIdx.x;
  if (i < 65536) {
    // KV[mt][f][l][j]: f<4 -> KF ks=f: c=f*16+(l>>5)*8+j, m=mt*32+(l&31)
    //                  f>=4 -> VF idx=f-4 (mh=idx>>1, ct=idx&1):
    //                          c=(idx&1)*32+(l&31), m=mt*32+(idx>>1)*16+(l>>5)*8+j
    const int j = i & 7, l = (i >> 3) & 63, f = (i >> 9) & 7, mt = i >> 12;
    float v;
    if (f < 4) {
      const int c = f * 16 + ((l >> 5) << 3) + j;
      const int m = mt * 32 + (l & 31);
      v = mb[c * MSLOT + m];
    } else {
      const int idx = f - 4;
      const int c = (idx & 1) * 32 + (l & 31);
      const int m = mt * 32 + (idx >> 1) * 16 + ((l >> 5) << 3) + j;
      v = mb[c * MSLOT + m];
    }
    wbw[BW_KV + i] = f2b(v);
  } else {                                   // WZF[ot][ks][l][j]: o=ot*32+(l&31), c=ks*16+(l>>5)*8+j
    const int i3 = i - 65536;
    const int j = i3 & 7, l = (i3 >> 3) & 63, ks = (i3 >> 9) & 3, ot = i3 >> 11;
    const int o = ot * 32 + (l & 31);
    const int c = ks * 16 + ((l >> 5) << 3) + j;
    wbw[BW_WZF + i3] = f2b(wz_w[o * 64 + c]);
  }
}

// ---------------- kernel 2: fold GN + scale into bf16 phi weights, emit frag-ordered WFF ----------------
__global__ __launch_bounds__(256) void k_prep(const float* __restrict__ phi_w,
                                              const float* __restrict__ phi_b,
                                              const float* __restrict__ gamma,
                                              const float* __restrict__ beta,
                                              float* __restrict__ ws) {
  const int b = blockIdx.x;
  const int o = threadIdx.x & 63;
  const int quad = threadIdx.x >> 6;
  __shared__ u16 wrow[64 * 64];
  __shared__ float offp[256];
  float offacc = 0.f;
#pragma unroll
  for (int ci = 0; ci < 16; ++ci) {
    const int c = quad * 16 + ci;
    const int g = c >> 1;
    const float mean = ws[WS_STATS + (b * 32 + g) * 2];
    const float rstd = ws[WS_STATS + (b * 32 + g) * 2 + 1];
    const float a = gamma[c] * rstd;
    const float d = beta[c] - mean * a;
    const float wv = phi_w[o * 64 + c];
    wrow[o * 64 + c] = f2b(wv * a * QSCALE);
    offacc += wv * d;
  }
  offp[threadIdx.x] = offacc;
  __syncthreads();
  if (quad == 0) {
    const float off = offp[o] + offp[64 + o] + offp[128 + o] + offp[192 + o];
    ws[WS_OFF + b * 64 + o] = (off + phi_b[o]) * QSCALE;
  }
  u16* wff = (u16*)(ws + WS_BF16) + BW_WFF + (size_t)b * 4096;
#pragma unroll
  for (int k = 0; k < 16; ++k) {
    const int il = threadIdx.x * 16 + k;      // [ot][ks][l][j]
    const int j = il & 7, l = (il >> 3) & 63, ks = (il >> 9) & 3, ot = il >> 11;
    const int oo = ot * 32 + (l & 31);
    const int c = ks * 16 + ((l >> 5) << 3) + j;
    wff[il] = wrow[oo * 64 + c];
  }
}

// ---------------- kernel 3: 32 px/wave + LDS K/V staging (r10 shape x r13 staging) ----------------
// r13 post-mortem: 64px/wave costs ~200 unified regs -> only 2 waves/SIMD
// resident; memory latency unhidden (~65% stall). With K/V now staged in LDS
// per BLOCK, the K/V-sharing rationale for 64px waves is gone: 32px/wave
// (r10's proven 108-unified-reg shape, 4 waves/SIMD under (256,4)) + staging
// keeps the 4x K/V traffic cut AND doubles resident waves. Grid 1024 blocks,
// 4 blocks/CU x 16KB LDS. Spill tripwire: WRITE_SIZE must stay 32768 KB.
__global__ __launch_bounds__(256, 4) void k_main(const float* __restrict__ x,
                                                 const float* __restrict__ ws,
                                                 const float* __restrict__ wz_b,
                                                 float* __restrict__ out) {
  const int b    = blockIdx.x >> 5;
  const int tile = blockIdx.x & 31;
  const int w    = threadIdx.x >> 6;
  const int lane = threadIdx.x & 63;
  const int l5 = lane & 31;
  const int hi = lane >> 5;
  const int p  = tile * 128 + w * 32 + l5;    // this lane's pixel column

  const u16* wb = (const u16*)(ws + WS_BF16);
  const float* xb = x + (size_t)b * CCH * HW;

  __shared__ __align__(16) u16 kv[2][8][512];   // 16KB double-buffered K/V tile

  // stage 8KB tile mt into buffer nb: wave w moves fragments w*2, w*2+1
#define STAGE(mt_, nb_)                                                          \
  {                                                                              \
    _Pragma("unroll")                                                            \
    for (int k = 0; k < 2; ++k) {                                                \
      const int f = w * 2 + k;                                                   \
      const u16* src = wb + BW_KV + ((size_t)(mt_) * 8 + f) * 512 + lane * 8;    \
      __builtin_amdgcn_global_load_lds(                                          \
          (const __attribute__((address_space(1))) void*)src,                    \
          (__attribute__((address_space(3))) void*)&kv[nb_][f][0], 16, 0, 0);    \
    }                                                                            \
  }

  STAGE(0, 0);   // prologue: tile 0 -> buf 0 (drained by the barrier below)

  // ---- phase A: x -> B-frags in-register; phi = Wfold @ x + off -> Q frags ----
  s16x8 q[4];
  {
    s16x8 bx[4];
#pragma unroll
    for (int ks = 0; ks < 4; ++ks) {
      const float* xc = xb + (size_t)(ks * 16 + hi * 8) * HW + p;
      float v[8];
#pragma unroll
      for (int j = 0; j < 8; ++j) v[j] = xc[(size_t)j * HW];
      u32x4 pk = {pack2(v[0], v[1]), pack2(v[2], v[3]),
                  pack2(v[4], v[5]), pack2(v[6], v[7])};
      bx[ks] = __builtin_bit_cast(s16x8, pk);
    }
    const float* offb = ws + WS_OFF + b * 64;
#pragma unroll
    for (int ot = 0; ot < 2; ++ot) {
      f32x16 acc = zero16();
#pragma unroll
      for (int ks = 0; ks < 4; ++ks) {
        const s16x8 a = *(const s16x8*)(wb + BW_WFF + ((((size_t)b * 2 + ot) * 4 + ks) * 64 + lane) * 8);
        acc = __builtin_amdgcn_mfma_f32_32x32x16_bf16(a, bx[ks], acc, 0, 0, 0);
      }
      float e[16];
#pragma unroll
      for (int rq = 0; rq < 4; ++rq) {
        const float4 offv = *(const float4*)(offb + ot * 32 + rq * 8 + hi * 4);
#pragma unroll
        for (int rr = 0; rr < 4; ++rr) e[rq * 4 + rr] = acc[rq * 4 + rr] + ((const float*)&offv)[rr];
      }
      d2b(e, q[ot * 2], q[ot * 2 + 1]);
    }
  }

  // ---- attention: full M=512 per wave; K/V from LDS, dbuf-staged ----
  f32x16 Y[2];
#pragma unroll
  for (int ct = 0; ct < 2; ++ct) Y[ct] = zero16();
  float Lacc = 0.f;

  __syncthreads();   // stage(0) complete (compiler drains vmcnt before s_barrier)

#pragma unroll 2
  for (int mt = 0; mt < 16; ++mt) {
    const int cb = mt & 1;
    if (mt < 15) STAGE(mt + 1, cb ^ 1);   // issue next tile early; drains at barrier below

    s16x8 kf[4], vf[4];
#pragma unroll
    for (int ks = 0; ks < 4; ++ks)
      kf[ks] = *(const s16x8*)&kv[cb][ks][(size_t)lane * 8];
#pragma unroll
    for (int i = 0; i < 4; ++i)
      vf[i] = *(const s16x8*)&kv[cb][4 + i][(size_t)lane * 8];

    f32x16 s = zero16();
#pragma unroll
    for (int ks = 0; ks < 4; ++ks)
      s = __builtin_amdgcn_mfma_f32_32x32x16_bf16(kf[ks], q[ks], s, 0, 0, 0);
    float e[16];
    float ls = 0.f;
#pragma unroll
    for (int r = 0; r < 16; ++r) { e[r] = exp2f(s[r]); ls += e[r]; }
    Lacc += ls;
    s16x8 pf0, pf1;
    d2b(e, pf0, pf1);
#pragma unroll
    for (int ct = 0; ct < 2; ++ct) {
      Y[ct] = __builtin_amdgcn_mfma_f32_32x32x16_bf16(vf[ct],     pf0, Y[ct], 0, 0, 0);
      Y[ct] = __builtin_amdgcn_mfma_f32_32x32x16_bf16(vf[2 + ct], pf1, Y[ct], 0, 0, 0);
    }
    __syncthreads();  // drains next-tile stage (flew during compute) + guards buf reuse
  }

  const float Ltot = Lacc + __shfl_xor(Lacc, 32, 64);
  const float invL = 1.f / Ltot;

  // ---- Y -> wz B-frags (normalize + transpose in-register) ----
  s16x8 by[4];
#pragma unroll
  for (int ct = 0; ct < 2; ++ct) {
    float e[16];
#pragma unroll
    for (int r = 0; r < 16; ++r) e[r] = Y[ct][r] * invL;
    d2b(e, by[ct * 2], by[ct * 2 + 1]);
  }

  // ---- phase D: out = wz @ y + wz_b + x ----
  const float* xr = xb + p;
  float* ob = out + (size_t)b * CCH * HW + p;
#pragma unroll
  for (int ot = 0; ot < 2; ++ot) {
    f32x16 acc = zero16();
#pragma unroll
    for (int ks = 0; ks < 4; ++ks) {
      const s16x8 a = *(const s16x8*)(wb + BW_WZF + (((size_t)ot * 4 + ks) * 64 + lane) * 8);
      acc = __builtin_amdgcn_mfma_f32_32x32x16_bf16(a, by[ks], acc, 0, 0, 0);
    }
#pragma unroll
    for (int rq = 0; rq < 4; ++rq) {
      const int obase = ot * 32 + rq * 8 + hi * 4;
      const float4 bz = *(const float4*)(wz_b + obase);
#pragma unroll
      for (int rr = 0; rr < 4; ++rr) {
        const size_t idx = (size_t)(obase + rr) * HW;
        ob[idx] = acc[rq * 4 + rr] + ((const float*)&bz)[rr] + xr[idx];
      }
    }
  }
#undef STAGE
}

extern "C" void kernel_launch(void* const* d_in, const int* in_sizes, int n_in,
                              void* d_out, int out_size, void* d_ws, size_t ws_size,
                              hipStream_t stream) {
  const float* x     = (const float*)d_in[0];
  const float* gamma = (const float*)d_in[1];
  const float* beta  = (const float*)d_in[2];
  const float* phi_w = (const float*)d_in[3];
  const float* phi_b = (const float*)d_in[4];
  const float* mb    = (const float*)d_in[5];
  const float* wz_w  = (const float*)d_in[6];
  const float* wz_b  = (const float*)d_in[7];
  float* out = (float*)d_out;
  float* ws  = (float*)d_ws;

  k_pre<<<1296, 256, 0, stream>>>(x, mb, wz_w, ws);
  k_prep<<<32, 256, 0, stream>>>(phi_w, phi_b, gamma, beta, ws);
  k_main<<<NFRAME * 32, 256, 0, stream>>>(x, ws, wz_b, out);
}

// Round 15
// 48.858 us; speedup vs baseline: 3.3815x; 1.0026x over previous
//
#include <hip/hip_runtime.h>
#include <hip/hip_bf16.h>

// n=2,t=16 -> 32 frames; C=64; HW=4096; M=512; 32 groups (2 ch/group).
#define NFRAME 32
#define CCH 64
#define HW 4096
#define MSLOT 512

typedef __attribute__((ext_vector_type(8))) short s16x8;    // 8 bf16 MFMA A/B frag
typedef __attribute__((ext_vector_type(16))) float f32x16;  // 32x32 MFMA C/D frag
typedef __attribute__((ext_vector_type(4))) unsigned int u32x4;
typedef __attribute__((ext_vector_type(2))) unsigned int u32x2;
typedef unsigned short u16;
typedef unsigned int u32;

// f32 workspace offsets
#define WS_STATS 0          // 1024*2 f32
#define WS_OFF   2048       // 32*64 f32
#define WS_BF16  4096       // u16 region starts here (float offset)
// u16 offsets inside bf16 region
#define BW_KV    0                         // [16 mt][8 f][512]  f=0..3 KF ks, f=4..7 VF (mh*2+ct)
#define BW_WZF   65536                     // [2 ot][4 ks][64 l][8]   wz A-frags
#define BW_WFF   69632                     // [32 b][2 ot][4 ks][64 l][8] phi A-frags

// exp2-domain scale: 1/sqrt(64) * log2(e)
#define QSCALE 0.18033688011112042f

static __device__ __forceinline__ u16 f2b(float f) {
  __hip_bfloat16 h = __float2bfloat16(f);
  return *reinterpret_cast<u16*>(&h);
}
// bf16 pair pack via v_cvt_pk_bf16_f32 (lane-local pure VALU op; RNE; safe as
// non-volatile asm — r5's miscompile was CROSS-LANE asm, this is arithmetic).
static __device__ __forceinline__ u32 pack2(float a, float b) {
  u32 r;
  asm("v_cvt_pk_bf16_f32 %0, %1, %2" : "=v"(r) : "v"(a), "v"(b));
  return r;
}
static __device__ __forceinline__ f32x16 zero16() {
  f32x16 z;
#pragma unroll
  for (int r = 0; r < 16; ++r) z[r] = 0.f;
  return z;
}
// D-layout -> B-frag transpose (verified r6): input 16 f32 regs e[] holding
// D[row rmap(r,hi)][col l5]; output B-frags f0 (k=0..15), f1 (k=16..31),
// lane row = l5. cvt_pk packs + convergent permlane32_swap builtin.
static __device__ __forceinline__ void d2b(const float* e, s16x8& f0, s16x8& f1) {
#pragma unroll
  for (int mh = 0; mh < 2; ++mh) {
    const u32 P0 = pack2(e[mh * 8 + 0], e[mh * 8 + 1]);
    const u32 P1 = pack2(e[mh * 8 + 2], e[mh * 8 + 3]);
    const u32 Q0 = pack2(e[mh * 8 + 4], e[mh * 8 + 5]);
    const u32 Q1 = pack2(e[mh * 8 + 6], e[mh * 8 + 7]);
    const u32x2 s0 = __builtin_amdgcn_permlane32_swap(P0, Q0, false, false);
    const u32x2 s1 = __builtin_amdgcn_permlane32_swap(P1, Q1, false, false);
    u32x4 bw = {s0[0], s1[0], s0[1], s1[1]};
    if (mh == 0) f0 = __builtin_bit_cast(s16x8, bw);
    else         f1 = __builtin_bit_cast(s16x8, bw);
  }
}

// ---------------- kernel 1: GroupNorm stats (blocks 0..1023) + KV/wz frag tables (1024..1295) ----------------
__global__ __launch_bounds__(256) void k_pre(const float* __restrict__ x,
                                             const float* __restrict__ mb,
                                             const float* __restrict__ wz_w,
                                             float* __restrict__ ws) {
  if (blockIdx.x < 1024) {
    const int bg = blockIdx.x;
    const float4* xp = (const float4*)(x + (size_t)bg * 8192);
    const int t = threadIdx.x;
    float s = 0.f, s2 = 0.f;
#pragma unroll
    for (int i = 0; i < 8; ++i) {
      float4 v = xp[t + i * 256];
      s  += v.x + v.y + v.z + v.w;
      s2 += v.x * v.x + v.y * v.y + v.z * v.z + v.w * v.w;
    }
    for (int off = 32; off; off >>= 1) {
      s  += __shfl_down(s,  off, 64);
      s2 += __shfl_down(s2, off, 64);
    }
    __shared__ float ls[8];
    const int wid = t >> 6;
    if ((t & 63) == 0) { ls[wid * 2] = s; ls[wid * 2 + 1] = s2; }
    __syncthreads();
    if (t == 0) {
      float S = 0.f, S2 = 0.f;
#pragma unroll
      for (int w = 0; w < 4; ++w) { S += ls[w * 2]; S2 += ls[w * 2 + 1]; }
      float mean = S * (1.f / 8192.f);
      float var  = S2 * (1.f / 8192.f) - mean * mean;
      float rstd = rsqrtf(var + 1e-6f);
      ws[WS_STATS + bg * 2]     = mean;
      ws[WS_STATS + bg * 2 + 1] = rstd;
    }
    return;
  }
  // fragment tables
  u16* wbw = (u16*)(ws + WS_BF16);
  const int i = (blockIdx.x - 1024) * 256 + threadIdx.x;
  if (i < 65536) {
    // KV[mt][f][l][j]: f<4 -> KF ks=f: c=f*16+(l>>5)*8+j, m=mt*32+(l&31)
    //                  f>=4 -> VF idx=f-4 (mh=idx>>1, ct=idx&1):
    //                          c=(idx&1)*32+(l&31), m=mt*32+(idx>>1)*16+(l>>5)*8+j
    const int j = i & 7, l = (i >> 3) & 63, f = (i >> 9) & 7, mt = i >> 12;
    float v;
    if (f < 4) {
      const int c = f * 16 + ((l >> 5) << 3) + j;
      const int m = mt * 32 + (l & 31);
      v = mb[c * MSLOT + m];
    } else {
      const int idx = f - 4;
      const int c = (idx & 1) * 32 + (l & 31);
      const int m = mt * 32 + (idx >> 1) * 16 + ((l >> 5) << 3) + j;
      v = mb[c * MSLOT + m];
    }
    wbw[BW_KV + i] = f2b(v);
  } else {                                   // WZF[ot][ks][l][j]: o=ot*32+(l&31), c=ks*16+(l>>5)*8+j
    const int i3 = i - 65536;
    const int j = i3 & 7, l = (i3 >> 3) & 63, ks = (i3 >> 9) & 3, ot = i3 >> 11;
    const int o = ot * 32 + (l & 31);
    const int c = ks * 16 + ((l >> 5) << 3) + j;
    wbw[BW_WZF + i3] = f2b(wz_w[o * 64 + c]);
  }
}

// ---------------- kernel 2: fold GN + scale into bf16 phi weights, emit frag-ordered WFF ----------------
__global__ __launch_bounds__(256) void k_prep(const float* __restrict__ phi_w,
                                              const float* __restrict__ phi_b,
                                              const float* __restrict__ gamma,
                                              const float* __restrict__ beta,
                                              float* __restrict__ ws) {
  const int b = blockIdx.x;
  const int o = threadIdx.x & 63;
  const int quad = threadIdx.x >> 6;
  __shared__ u16 wrow[64 * 64];
  __shared__ float offp[256];
  float offacc = 0.f;
#pragma unroll
  for (int ci = 0; ci < 16; ++ci) {
    const int c = quad * 16 + ci;
    const int g = c >> 1;
    const float mean = ws[WS_STATS + (b * 32 + g) * 2];
    const float rstd = ws[WS_STATS + (b * 32 + g) * 2 + 1];
    const float a = gamma[c] * rstd;
    const float d = beta[c] - mean * a;
    const float wv = phi_w[o * 64 + c];
    wrow[o * 64 + c] = f2b(wv * a * QSCALE);
    offacc += wv * d;
  }
  offp[threadIdx.x] = offacc;
  __syncthreads();
  if (quad == 0) {
    const float off = offp[o] + offp[64 + o] + offp[128 + o] + offp[192 + o];
    ws[WS_OFF + b * 64 + o] = (off + phi_b[o]) * QSCALE;
  }
  u16* wff = (u16*)(ws + WS_BF16) + BW_WFF + (size_t)b * 4096;
#pragma unroll
  for (int k = 0; k < 16; ++k) {
    const int il = threadIdx.x * 16 + k;      // [ot][ks][l][j]
    const int j = il & 7, l = (il >> 3) & 63, ks = (il >> 9) & 3, ot = il >> 11;
    const int oo = ot * 32 + (l & 31);
    const int c = ks * 16 + ((l >> 5) << 3) + j;
    wff[il] = wrow[oo * 64 + c];
  }
}

// ---------------- kernel 3: 32 px/wave + LDS K/V staging; READS BEFORE STAGE ----------------
// r14 post-mortem: body order was STAGE(mt+1) -> ds_read. Stage writes and
// ds_reads touch the same LDS object; compiler can't prove buffers disjoint,
// so it inserts a conservative s_waitcnt vmcnt(0) BEFORE the ds_reads — i.e.
// right after the prefetch issue. The "prefetch" latency sat on the critical
// path of every iteration. r15 (two statements swapped): ds_read current tile
// FIRST (vmcnt already drained by prior barrier -> no wait), THEN issue
// STAGE(mt+1); it flies under ~500cyc of compute and drains at the end-of-iter
// barrier. Everything else identical to r14.
__global__ __launch_bounds__(256, 4) void k_main(const float* __restrict__ x,
                                                 const float* __restrict__ ws,
                                                 const float* __restrict__ wz_b,
                                                 float* __restrict__ out) {
  const int b    = blockIdx.x >> 5;
  const int tile = blockIdx.x & 31;
  const int w    = threadIdx.x >> 6;
  const int lane = threadIdx.x & 63;
  const int l5 = lane & 31;
  const int hi = lane >> 5;
  const int p  = tile * 128 + w * 32 + l5;    // this lane's pixel column

  const u16* wb = (const u16*)(ws + WS_BF16);
  const float* xb = x + (size_t)b * CCH * HW;

  __shared__ __align__(16) u16 kv[2][8][512];   // 16KB double-buffered K/V tile

  // stage 8KB tile mt into buffer nb: wave w moves fragments w*2, w*2+1
#define STAGE(mt_, nb_)                                                          \
  {                                                                              \
    _Pragma("unroll")                                                            \
    for (int k = 0; k < 2; ++k) {                                                \
      const int f = w * 2 + k;                                                   \
      const u16* src = wb + BW_KV + ((size_t)(mt_) * 8 + f) * 512 + lane * 8;    \
      __builtin_amdgcn_global_load_lds(                                          \
          (const __attribute__((address_space(1))) void*)src,                    \
          (__attribute__((address_space(3))) void*)&kv[nb_][f][0], 16, 0, 0);    \
    }                                                                            \
  }

  STAGE(0, 0);   // prologue: tile 0 -> buf 0 (hidden under phase A, drained at barrier)

  // ---- phase A: x -> B-frags in-register; phi = Wfold @ x + off -> Q frags ----
  s16x8 q[4];
  {
    s16x8 bx[4];
#pragma unroll
    for (int ks = 0; ks < 4; ++ks) {
      const float* xc = xb + (size_t)(ks * 16 + hi * 8) * HW + p;
      float v[8];
#pragma unroll
      for (int j = 0; j < 8; ++j) v[j] = xc[(size_t)j * HW];
      u32x4 pk = {pack2(v[0], v[1]), pack2(v[2], v[3]),
                  pack2(v[4], v[5]), pack2(v[6], v[7])};
      bx[ks] = __builtin_bit_cast(s16x8, pk);
    }
    const float* offb = ws + WS_OFF + b * 64;
#pragma unroll
    for (int ot = 0; ot < 2; ++ot) {
      f32x16 acc = zero16();
#pragma unroll
      for (int ks = 0; ks < 4; ++ks) {
        const s16x8 a = *(const s16x8*)(wb + BW_WFF + ((((size_t)b * 2 + ot) * 4 + ks) * 64 + lane) * 8);
        acc = __builtin_amdgcn_mfma_f32_32x32x16_bf16(a, bx[ks], acc, 0, 0, 0);
      }
      float e[16];
#pragma unroll
      for (int rq = 0; rq < 4; ++rq) {
        const float4 offv = *(const float4*)(offb + ot * 32 + rq * 8 + hi * 4);
#pragma unroll
        for (int rr = 0; rr < 4; ++rr) e[rq * 4 + rr] = acc[rq * 4 + rr] + ((const float*)&offv)[rr];
      }
      d2b(e, q[ot * 2], q[ot * 2 + 1]);
    }
  }

  // ---- attention: full M=512 per wave; K/V from LDS, dbuf-staged ----
  f32x16 Y[2];
#pragma unroll
  for (int ct = 0; ct < 2; ++ct) Y[ct] = zero16();
  float Lacc = 0.f;

  __syncthreads();   // stage(0) complete (compiler drains vmcnt before s_barrier)

#pragma unroll 2
  for (int mt = 0; mt < 16; ++mt) {
    const int cb = mt & 1;

    // ds_read CURRENT tile first — vmcnt drained at loop-top barrier, no wait
    s16x8 kf[4], vf[4];
#pragma unroll
    for (int ks = 0; ks < 4; ++ks)
      kf[ks] = *(const s16x8*)&kv[cb][ks][(size_t)lane * 8];
#pragma unroll
    for (int i = 0; i < 4; ++i)
      vf[i] = *(const s16x8*)&kv[cb][4 + i][(size_t)lane * 8];

    // THEN issue next-tile stage: flies under the compute below, drains at barrier
    if (mt < 15) STAGE(mt + 1, cb ^ 1);

    f32x16 s = zero16();
#pragma unroll
    for (int ks = 0; ks < 4; ++ks)
      s = __builtin_amdgcn_mfma_f32_32x32x16_bf16(kf[ks], q[ks], s, 0, 0, 0);
    float e[16];
    float ls = 0.f;
#pragma unroll
    for (int r = 0; r < 16; ++r) { e[r] = exp2f(s[r]); ls += e[r]; }
    Lacc += ls;
    s16x8 pf0, pf1;
    d2b(e, pf0, pf1);
#pragma unroll
    for (int ct = 0; ct < 2; ++ct) {
      Y[ct] = __builtin_amdgcn_mfma_f32_32x32x16_bf16(vf[ct],     pf0, Y[ct], 0, 0, 0);
      Y[ct] = __builtin_amdgcn_mfma_f32_32x32x16_bf16(vf[2 + ct], pf1, Y[ct], 0, 0, 0);
    }
    __syncthreads();  // drains next-tile stage (flew during compute) + guards buf reuse
  }

  const float Ltot = Lacc + __shfl_xor(Lacc, 32, 64);
  const float invL = 1.f / Ltot;

  // ---- Y -> wz B-frags (normalize + transpose in-register) ----
  s16x8 by[4];
#pragma unroll
  for (int ct = 0; ct < 2; ++ct) {
    float e[16];
#pragma unroll
    for (int r = 0; r < 16; ++r) e[r] = Y[ct][r] * invL;
    d2b(e, by[ct * 2], by[ct * 2 + 1]);
  }

  // ---- phase D: out = wz @ y + wz_b + x ----
  const float* xr = xb + p;
  float* ob = out + (size_t)b * CCH * HW + p;
#pragma unroll
  for (int ot = 0; ot < 2; ++ot) {
    f32x16 acc = zero16();
#pragma unroll
    for (int ks = 0; ks < 4; ++ks) {
      const s16x8 a = *(const s16x8*)(wb + BW_WZF + (((size_t)ot * 4 + ks) * 64 + lane) * 8);
      acc = __builtin_amdgcn_mfma_f32_32x32x16_bf16(a, by[ks], acc, 0, 0, 0);
    }
#pragma unroll
    for (int rq = 0; rq < 4; ++rq) {
      const int obase = ot * 32 + rq * 8 + hi * 4;
      const float4 bz = *(const float4*)(wz_b + obase);
#pragma unroll
      for (int rr = 0; rr < 4; ++rr) {
        const size_t idx = (size_t)(obase + rr) * HW;
        ob[idx] = acc[rq * 4 + rr] + ((const float*)&bz)[rr] + xr[idx];
      }
    }
  }
#undef STAGE
}

extern "C" void kernel_launch(void* const* d_in, const int* in_sizes, int n_in,
                              void* d_out, int out_size, void* d_ws, size_t ws_size,
                              hipStream_t stream) {
  const float* x     = (const float*)d_in[0];
  const float* gamma = (const float*)d_in[1];
  const float* beta  = (const float*)d_in[2];
  const float* phi_w = (const float*)d_in[3];
  const float* phi_b = (const float*)d_in[4];
  const float* mb    = (const float*)d_in[5];
  const float* wz_w  = (const float*)d_in[6];
  const float* wz_b  = (const float*)d_in[7];
  float* out = (float*)d_out;
  float* ws  = (float*)d_ws;

  k_pre<<<1296, 256, 0, stream>>>(x, mb, wz_w, ws);
  k_prep<<<32, 256, 0, stream>>>(phi_w, phi_b, gamma, beta, ws);
  k_main<<<NFRAME * 32, 256, 0, stream>>>(x, ws, wz_b, out);
}